// Round 1
// baseline (533.205 us; speedup 1.0000x reference)
//
#include <hip/hip_runtime.h>

#define NNODES 50000
#define NEDGES 800000
#define KDIM   256      // in/hidden feature dim (GEMM K)
#define FH     256      // hidden feats
#define FOUT   128      // out feats

// ---------------- degree + norm ----------------
__global__ __launch_bounds__(256) void deg_kernel(const int* __restrict__ src,
                                                  const int* __restrict__ dst,
                                                  int* __restrict__ deg_out,
                                                  int* __restrict__ deg_in) {
    int e = blockIdx.x * 256 + threadIdx.x;
    if (e < NEDGES) {
        atomicAdd(&deg_out[src[e]], 1);
        atomicAdd(&deg_in[dst[e]], 1);
    }
}

__global__ __launch_bounds__(256) void norm_kernel(const int* __restrict__ deg_out,
                                                   const int* __restrict__ deg_in,
                                                   float* __restrict__ norm_src,
                                                   float* __restrict__ norm_dst) {
    int i = blockIdx.x * 256 + threadIdx.x;
    if (i < NNODES) {
        int dso = deg_out[i]; if (dso < 1) dso = 1;
        int dsi = deg_in[i];  if (dsi < 1) dsi = 1;
        norm_src[i] = 1.0f / sqrtf((float)dso);
        norm_dst[i] = 1.0f / sqrtf((float)dsi);
    }
}

// ---------------- exclusive scan of deg_in -> row_ptr ----------------
__global__ __launch_bounds__(256) void scan1(const int* __restrict__ deg_in,
                                             int* __restrict__ excl,   // row_ptr used as temp
                                             int* __restrict__ blockSums) {
    __shared__ int s[256];
    int tid = threadIdx.x;
    int i = blockIdx.x * 256 + tid;
    int v = (i < NNODES) ? deg_in[i] : 0;
    s[tid] = v;
    __syncthreads();
    for (int off = 1; off < 256; off <<= 1) {
        int t = (tid >= off) ? s[tid - off] : 0;
        __syncthreads();
        s[tid] += t;
        __syncthreads();
    }
    excl[i] = s[tid] - v;               // block-local exclusive
    if (tid == 255) blockSums[blockIdx.x] = s[255];
}

__global__ __launch_bounds__(256) void scan2(int* __restrict__ blockSums, int nblocks) {
    __shared__ int s[256];
    int tid = threadIdx.x;
    int v = (tid < nblocks) ? blockSums[tid] : 0;
    s[tid] = v;
    __syncthreads();
    for (int off = 1; off < 256; off <<= 1) {
        int t = (tid >= off) ? s[tid - off] : 0;
        __syncthreads();
        s[tid] += t;
        __syncthreads();
    }
    if (tid < nblocks) blockSums[tid] = s[tid] - v;   // exclusive
}

__global__ __launch_bounds__(256) void scan3(int* __restrict__ row_ptr,
                                             const int* __restrict__ blockSums,
                                             int* __restrict__ cursor) {
    int i = blockIdx.x * 256 + threadIdx.x;
    if (i < NNODES) {
        int r = row_ptr[i] + blockSums[blockIdx.x];
        row_ptr[i] = r;
        cursor[i] = r;
    }
    if (i == 0) row_ptr[NNODES] = NEDGES;
}

__global__ __launch_bounds__(256) void fill_csr(const int* __restrict__ src,
                                                const int* __restrict__ dst,
                                                int* __restrict__ cursor,
                                                int* __restrict__ csr_src) {
    int e = blockIdx.x * 256 + threadIdx.x;
    if (e < NEDGES) {
        int d = dst[e];
        int p = atomicAdd(&cursor[d], 1);
        csr_src[p] = src[e];
    }
}

// ---------------- fp32 GEMM: C[M,ncols] = (A[M,256] * norm[m]) @ W[256,ncols] ----------------
// BM=64, BN=64, BK=16, 256 threads, 4x4 per-thread micro-tile.
__global__ __launch_bounds__(256) void gemm_norm(const float* __restrict__ A,
                                                 const float* __restrict__ W,
                                                 const float* __restrict__ norm,
                                                 float* __restrict__ C,
                                                 int ncols) {
    __shared__ __align__(16) float As[16][64];
    __shared__ __align__(16) float Bs[16][64];

    const int tid = threadIdx.x;
    const int bx = blockIdx.x;      // n tile
    const int by = blockIdx.y;      // m tile
    const int m0 = by * 64;

    // A staging: thread -> (row, k4): 64 rows x 4 float4 across K-tile of 16
    const int arow = tid >> 2;
    const int ak4  = (tid & 3) << 2;
    const int gArow = m0 + arow;
    const bool aValid = (gArow < NNODES);
    const float scale = aValid ? norm[gArow] : 0.0f;
    const float* Aptr = A + (size_t)(aValid ? gArow : 0) * KDIM + ak4;

    // B staging: thread -> (row 0..15, col4 0..15)
    const int brow = tid >> 4;
    const int bc4  = (tid & 15) << 2;
    const float* Wptr = W + (size_t)brow * ncols + bx * 64 + bc4;

    const int tx = tid & 15;
    const int ty = tid >> 4;

    float acc[4][4] = {};

    for (int kk = 0; kk < KDIM; kk += 16) {
        float4 a = make_float4(0.f, 0.f, 0.f, 0.f);
        if (aValid) a = *(const float4*)(Aptr + kk);
        a.x *= scale; a.y *= scale; a.z *= scale; a.w *= scale;
        float4 b = *(const float4*)(Wptr + (size_t)kk * ncols);

        __syncthreads();
        As[ak4 + 0][arow] = a.x;
        As[ak4 + 1][arow] = a.y;
        As[ak4 + 2][arow] = a.z;
        As[ak4 + 3][arow] = a.w;
        *(float4*)(&Bs[brow][bc4]) = b;
        __syncthreads();

#pragma unroll
        for (int k = 0; k < 16; ++k) {
            const float4 av = *(const float4*)(&As[k][ty << 2]);
            const float4 bv = *(const float4*)(&Bs[k][tx << 2]);
            float a4[4] = {av.x, av.y, av.z, av.w};
            float b4[4] = {bv.x, bv.y, bv.z, bv.w};
#pragma unroll
            for (int i = 0; i < 4; ++i)
#pragma unroll
                for (int j = 0; j < 4; ++j)
                    acc[i][j] = fmaf(a4[i], b4[j], acc[i][j]);
        }
    }

#pragma unroll
    for (int i = 0; i < 4; ++i) {
        int m = m0 + (ty << 2) + i;
        if (m < NNODES) {
            float4 o = make_float4(acc[i][0], acc[i][1], acc[i][2], acc[i][3]);
            *(float4*)(&C[(size_t)m * ncols + bx * 64 + (tx << 2)]) = o;
        }
    }
}

// ---------------- aggregation: out[n] = (sum_{e in in(n)} H[src_e]) * norm_dst[n] + bias; opt relu
// VEC=4 -> F=256 (float4/lane), VEC=2 -> F=128 (float2/lane). One wave per node, 4 nodes/block.
template <int VEC>
__global__ __launch_bounds__(256) void agg_kernel(const float* __restrict__ H,
                                                  const int* __restrict__ row_ptr,
                                                  const int* __restrict__ csr_src,
                                                  const float* __restrict__ norm_dst,
                                                  const float* __restrict__ bias,
                                                  float* __restrict__ out,
                                                  int doRelu) {
    const int F = 64 * VEC;
    int node = blockIdx.x * 4 + (threadIdx.x >> 6);
    if (node >= NNODES) return;
    int lane = threadIdx.x & 63;
    int e0 = row_ptr[node];
    int e1 = row_ptr[node + 1];

    float acc[VEC];
#pragma unroll
    for (int j = 0; j < VEC; ++j) acc[j] = 0.0f;

    const float* Hl = H + lane * VEC;

    int e = e0;
    // 4-deep unroll for memory-level parallelism
    for (; e + 3 < e1; e += 4) {
        int s0 = csr_src[e], s1 = csr_src[e + 1], s2 = csr_src[e + 2], s3 = csr_src[e + 3];
        const float* p0 = Hl + (size_t)s0 * F;
        const float* p1 = Hl + (size_t)s1 * F;
        const float* p2 = Hl + (size_t)s2 * F;
        const float* p3 = Hl + (size_t)s3 * F;
        if (VEC == 4) {
            float4 v0 = *(const float4*)p0;
            float4 v1 = *(const float4*)p1;
            float4 v2 = *(const float4*)p2;
            float4 v3 = *(const float4*)p3;
            acc[0] += v0.x + v1.x + v2.x + v3.x;
            acc[1] += v0.y + v1.y + v2.y + v3.y;
            acc[2] += v0.z + v1.z + v2.z + v3.z;
            acc[3] += v0.w + v1.w + v2.w + v3.w;
        } else {
            float2 v0 = *(const float2*)p0;
            float2 v1 = *(const float2*)p1;
            float2 v2 = *(const float2*)p2;
            float2 v3 = *(const float2*)p3;
            acc[0] += v0.x + v1.x + v2.x + v3.x;
            acc[1] += v0.y + v1.y + v2.y + v3.y;
        }
    }
    for (; e < e1; ++e) {
        int s = csr_src[e];
        const float* p = Hl + (size_t)s * F;
        if (VEC == 4) {
            float4 v = *(const float4*)p;
            acc[0] += v.x; acc[1] += v.y; acc[2] += v.z; acc[3] += v.w;
        } else {
            float2 v = *(const float2*)p;
            acc[0] += v.x; acc[1] += v.y;
        }
    }

    float nd = norm_dst[node];
    float o[VEC];
#pragma unroll
    for (int j = 0; j < VEC; ++j) {
        o[j] = fmaf(acc[j], nd, bias[lane * VEC + j]);
        if (doRelu) o[j] = fmaxf(o[j], 0.0f);
    }
    float* dst = out + (size_t)node * F + lane * VEC;
    if (VEC == 4) {
        *(float4*)dst = make_float4(o[0], o[1], o[2], o[3]);
    } else {
        *(float2*)dst = make_float2(o[0], o[1]);
    }
}

// ---------------- launch ----------------
extern "C" void kernel_launch(void* const* d_in, const int* in_sizes, int n_in,
                              void* d_out, int out_size, void* d_ws, size_t ws_size,
                              hipStream_t stream) {
    const float* x   = (const float*)d_in[0];
    const int*   src = (const int*)d_in[1];
    const int*   dst = (const int*)d_in[2];
    const float* W1  = (const float*)d_in[3];
    const float* b1  = (const float*)d_in[4];
    const float* W2  = (const float*)d_in[5];
    const float* b2  = (const float*)d_in[6];
    float* out = (float*)d_out;

    // workspace carve-up (256B aligned)
    char* ws = (char*)d_ws;
    size_t off = 0;
    auto alloc = [&](size_t bytes) {
        char* p = ws + off;
        off += (bytes + 255) & ~(size_t)255;
        return p;
    };
    float* norm_src  = (float*)alloc(NNODES * 4);
    float* norm_dst  = (float*)alloc(NNODES * 4);
    int*   deg_out   = (int*)alloc(NNODES * 4);
    int*   deg_in    = (int*)alloc(NNODES * 4);
    int*   row_ptr   = (int*)alloc((NNODES + 256) * 4);  // padded: scan1 writes up to 50175
    int*   cursor    = (int*)alloc(NNODES * 4);
    int*   blockSums = (int*)alloc(256 * 4);
    int*   csr_src   = (int*)alloc(NEDGES * 4);
    float* h         = (float*)alloc((size_t)NNODES * FH * 4);   // gemm1 out; reused as gemm2 out
    float* h1        = (float*)alloc((size_t)NNODES * FH * 4);   // agg1 out (post-relu)
    float* h2        = h;                                        // [NNODES, FOUT] reuse

    const int NB_N = (NNODES + 255) / 256;   // 196
    const int NB_E = (NEDGES + 255) / 256;   // 3125

    // zero degree counters (ws is poisoned 0xAA each call)
    hipMemsetAsync(deg_out, 0, 2 * NNODES * 4, stream);  // deg_out + deg_in adjacent? not guaranteed by carve-up
    hipMemsetAsync(deg_in, 0, NNODES * 4, stream);

    deg_kernel<<<NB_E, 256, 0, stream>>>(src, dst, deg_out, deg_in);
    norm_kernel<<<NB_N, 256, 0, stream>>>(deg_out, deg_in, norm_src, norm_dst);
    scan1<<<NB_N, 256, 0, stream>>>(deg_in, row_ptr, blockSums);
    scan2<<<1, 256, 0, stream>>>(blockSums, NB_N);
    scan3<<<NB_N, 256, 0, stream>>>(row_ptr, blockSums, cursor);
    fill_csr<<<NB_E, 256, 0, stream>>>(src, dst, cursor, csr_src);

    // layer 1: h = (x * norm_src) @ W1 ; h1 = relu(agg(h) * norm_dst + b1)
    gemm_norm<<<dim3(FH / 64, (NNODES + 63) / 64), 256, 0, stream>>>(x, W1, norm_src, h, FH);
    agg_kernel<4><<<(NNODES + 3) / 4, 256, 0, stream>>>(h, row_ptr, csr_src, norm_dst, b1, h1, 1);

    // layer 2: h2 = (h1 * norm_src) @ W2 ; out = agg(h2) * norm_dst + b2
    gemm_norm<<<dim3(FOUT / 64, (NNODES + 63) / 64), 256, 0, stream>>>(h1, W2, norm_src, h2, FOUT);
    agg_kernel<2><<<(NNODES + 3) / 4, 256, 0, stream>>>(h2, row_ptr, csr_src, norm_dst, b2, out, 0);
}

// Round 2
// 444.517 us; speedup vs baseline: 1.1995x; 1.1995x over previous
//
#include <hip/hip_runtime.h>

#define NNODES 50000
#define NEDGES 800000
#define KDIM   256      // in/hidden feature dim (GEMM K)
#define FH     256      // hidden feats
#define FOUT   128      // out feats

// ---------------- bf16 helpers (RNE) ----------------
__device__ __forceinline__ float bf2f(unsigned short u) {
    union { unsigned int i; float f; } v;
    v.i = ((unsigned int)u) << 16;
    return v.f;
}
__device__ __forceinline__ unsigned short f2bf(float f) {
    union { float f; unsigned int i; } v;
    v.f = f;
    unsigned int r = v.i + 0x7FFFu + ((v.i >> 16) & 1u);
    return (unsigned short)(r >> 16);
}

// ---------------- degree + norm ----------------
__global__ __launch_bounds__(256) void deg_kernel(const int* __restrict__ src,
                                                  const int* __restrict__ dst,
                                                  int* __restrict__ deg_out,
                                                  int* __restrict__ deg_in) {
    int e = blockIdx.x * 256 + threadIdx.x;
    if (e < NEDGES) {
        atomicAdd(&deg_out[src[e]], 1);
        atomicAdd(&deg_in[dst[e]], 1);
    }
}

__global__ __launch_bounds__(256) void norm_kernel(const int* __restrict__ deg_out,
                                                   const int* __restrict__ deg_in,
                                                   float* __restrict__ norm_src,
                                                   float* __restrict__ norm_dst) {
    int i = blockIdx.x * 256 + threadIdx.x;
    if (i < NNODES) {
        int dso = deg_out[i]; if (dso < 1) dso = 1;
        int dsi = deg_in[i];  if (dsi < 1) dsi = 1;
        norm_src[i] = 1.0f / sqrtf((float)dso);
        norm_dst[i] = 1.0f / sqrtf((float)dsi);
    }
}

// ---------------- exclusive scan of deg_in -> row_ptr ----------------
__global__ __launch_bounds__(256) void scan1(const int* __restrict__ deg_in,
                                             int* __restrict__ excl,
                                             int* __restrict__ blockSums) {
    __shared__ int s[256];
    int tid = threadIdx.x;
    int i = blockIdx.x * 256 + tid;
    int v = (i < NNODES) ? deg_in[i] : 0;
    s[tid] = v;
    __syncthreads();
    for (int off = 1; off < 256; off <<= 1) {
        int t = (tid >= off) ? s[tid - off] : 0;
        __syncthreads();
        s[tid] += t;
        __syncthreads();
    }
    excl[i] = s[tid] - v;
    if (tid == 255) blockSums[blockIdx.x] = s[255];
}

__global__ __launch_bounds__(256) void scan2(int* __restrict__ blockSums, int nblocks) {
    __shared__ int s[256];
    int tid = threadIdx.x;
    int v = (tid < nblocks) ? blockSums[tid] : 0;
    s[tid] = v;
    __syncthreads();
    for (int off = 1; off < 256; off <<= 1) {
        int t = (tid >= off) ? s[tid - off] : 0;
        __syncthreads();
        s[tid] += t;
        __syncthreads();
    }
    if (tid < nblocks) blockSums[tid] = s[tid] - v;
}

__global__ __launch_bounds__(256) void scan3(int* __restrict__ row_ptr,
                                             const int* __restrict__ blockSums,
                                             int* __restrict__ cursor) {
    int i = blockIdx.x * 256 + threadIdx.x;
    if (i < NNODES) {
        int r = row_ptr[i] + blockSums[blockIdx.x];
        row_ptr[i] = r;
        cursor[i] = r;
    }
    if (i == 0) row_ptr[NNODES] = NEDGES;
}

__global__ __launch_bounds__(256) void fill_csr(const int* __restrict__ src,
                                                const int* __restrict__ dst,
                                                int* __restrict__ cursor,
                                                int* __restrict__ csr_src) {
    int e = blockIdx.x * 256 + threadIdx.x;
    if (e < NEDGES) {
        int d = dst[e];
        int p = atomicAdd(&cursor[d], 1);
        csr_src[p] = src[e];
    }
}

// ---------------- fp32-accum GEMM: C_bf16[M,ncols] = (A[M,256] * norm[m]) @ W[256,ncols]
// BM=64, BN=64, BK=16, 256 threads, 4x4 per-thread micro-tile. A dtype templated.
template <typename TA>
__device__ __forceinline__ float4 loadA4(const TA* p);
template <>
__device__ __forceinline__ float4 loadA4<float>(const float* p) { return *(const float4*)p; }
template <>
__device__ __forceinline__ float4 loadA4<unsigned short>(const unsigned short* p) {
    ushort4 u = *(const ushort4*)p;
    return make_float4(bf2f(u.x), bf2f(u.y), bf2f(u.z), bf2f(u.w));
}

template <typename TA>
__global__ __launch_bounds__(256) void gemm_norm(const TA* __restrict__ A,
                                                 const float* __restrict__ W,
                                                 const float* __restrict__ norm,
                                                 unsigned short* __restrict__ C,
                                                 int ncols) {
    __shared__ __align__(16) float As[16][64];
    __shared__ __align__(16) float Bs[16][64];

    const int tid = threadIdx.x;
    const int bx = blockIdx.x;
    const int by = blockIdx.y;
    const int m0 = by * 64;

    const int arow = tid >> 2;
    const int ak4  = (tid & 3) << 2;
    const int gArow = m0 + arow;
    const bool aValid = (gArow < NNODES);
    const float scale = aValid ? norm[gArow] : 0.0f;
    const TA* Aptr = A + (size_t)(aValid ? gArow : 0) * KDIM + ak4;

    const int brow = tid >> 4;
    const int bc4  = (tid & 15) << 2;
    const float* Wptr = W + (size_t)brow * ncols + bx * 64 + bc4;

    const int tx = tid & 15;
    const int ty = tid >> 4;

    float acc[4][4] = {};

    for (int kk = 0; kk < KDIM; kk += 16) {
        float4 a = loadA4<TA>(Aptr + kk);
        a.x *= scale; a.y *= scale; a.z *= scale; a.w *= scale;
        float4 b = *(const float4*)(Wptr + (size_t)kk * ncols);

        __syncthreads();
        As[ak4 + 0][arow] = a.x;
        As[ak4 + 1][arow] = a.y;
        As[ak4 + 2][arow] = a.z;
        As[ak4 + 3][arow] = a.w;
        *(float4*)(&Bs[brow][bc4]) = b;
        __syncthreads();

#pragma unroll
        for (int k = 0; k < 16; ++k) {
            const float4 av = *(const float4*)(&As[k][ty << 2]);
            const float4 bv = *(const float4*)(&Bs[k][tx << 2]);
            float a4[4] = {av.x, av.y, av.z, av.w};
            float b4[4] = {bv.x, bv.y, bv.z, bv.w};
#pragma unroll
            for (int i = 0; i < 4; ++i)
#pragma unroll
                for (int j = 0; j < 4; ++j)
                    acc[i][j] = fmaf(a4[i], b4[j], acc[i][j]);
        }
    }

#pragma unroll
    for (int i = 0; i < 4; ++i) {
        int m = m0 + (ty << 2) + i;
        if (m < NNODES) {
            ushort4 o;
            o.x = f2bf(acc[i][0]);
            o.y = f2bf(acc[i][1]);
            o.z = f2bf(acc[i][2]);
            o.w = f2bf(acc[i][3]);
            *(ushort4*)(&C[(size_t)m * ncols + bx * 64 + (tx << 2)]) = o;
        }
    }
}

// ---------------- agg layer 1: bf16 in (F=256), bf16 out, relu.
// One wave per node, lane handles 4 consecutive feats (8B loads). 4 nodes/block.
__global__ __launch_bounds__(256) void agg1_kernel(const unsigned short* __restrict__ H,
                                                   const int* __restrict__ row_ptr,
                                                   const int* __restrict__ csr_src,
                                                   const float* __restrict__ norm_dst,
                                                   const float* __restrict__ bias,
                                                   unsigned short* __restrict__ out) {
    const int F = 256;
    int node = blockIdx.x * 4 + (threadIdx.x >> 6);
    if (node >= NNODES) return;
    int lane = threadIdx.x & 63;
    int f0 = lane * 4;
    int e0 = row_ptr[node];
    int e1 = row_ptr[node + 1];

    float acc0 = 0.f, acc1 = 0.f, acc2 = 0.f, acc3 = 0.f;
    const unsigned short* Hl = H + f0;

    int e = e0;
    for (; e + 3 < e1; e += 4) {
        int s0 = csr_src[e], s1 = csr_src[e + 1], s2 = csr_src[e + 2], s3 = csr_src[e + 3];
        ushort4 v0 = *(const ushort4*)(Hl + (size_t)s0 * F);
        ushort4 v1 = *(const ushort4*)(Hl + (size_t)s1 * F);
        ushort4 v2 = *(const ushort4*)(Hl + (size_t)s2 * F);
        ushort4 v3 = *(const ushort4*)(Hl + (size_t)s3 * F);
        acc0 += bf2f(v0.x) + bf2f(v1.x) + bf2f(v2.x) + bf2f(v3.x);
        acc1 += bf2f(v0.y) + bf2f(v1.y) + bf2f(v2.y) + bf2f(v3.y);
        acc2 += bf2f(v0.z) + bf2f(v1.z) + bf2f(v2.z) + bf2f(v3.z);
        acc3 += bf2f(v0.w) + bf2f(v1.w) + bf2f(v2.w) + bf2f(v3.w);
    }
    for (; e < e1; ++e) {
        int s = csr_src[e];
        ushort4 v = *(const ushort4*)(Hl + (size_t)s * F);
        acc0 += bf2f(v.x); acc1 += bf2f(v.y); acc2 += bf2f(v.z); acc3 += bf2f(v.w);
    }

    float nd = norm_dst[node];
    float o0 = fmaxf(fmaf(acc0, nd, bias[f0 + 0]), 0.0f);
    float o1 = fmaxf(fmaf(acc1, nd, bias[f0 + 1]), 0.0f);
    float o2 = fmaxf(fmaf(acc2, nd, bias[f0 + 2]), 0.0f);
    float o3 = fmaxf(fmaf(acc3, nd, bias[f0 + 3]), 0.0f);
    ushort4 o;
    o.x = f2bf(o0); o.y = f2bf(o1); o.z = f2bf(o2); o.w = f2bf(o3);
    *(ushort4*)(out + (size_t)node * F + f0) = o;
}

// ---------------- agg layer 2: bf16 in (F=128), fp32 out, no relu.
// Half-wave (32 lanes) per node, lane handles 4 feats (8B loads). 8 nodes/block.
__global__ __launch_bounds__(256) void agg2_kernel(const unsigned short* __restrict__ H,
                                                   const int* __restrict__ row_ptr,
                                                   const int* __restrict__ csr_src,
                                                   const float* __restrict__ norm_dst,
                                                   const float* __restrict__ bias,
                                                   float* __restrict__ out) {
    const int F = 128;
    int node = blockIdx.x * 8 + (threadIdx.x >> 5);
    if (node >= NNODES) return;
    int lane = threadIdx.x & 31;
    int f0 = lane * 4;
    int e0 = row_ptr[node];
    int e1 = row_ptr[node + 1];

    float acc0 = 0.f, acc1 = 0.f, acc2 = 0.f, acc3 = 0.f;
    const unsigned short* Hl = H + f0;

    int e = e0;
    for (; e + 3 < e1; e += 4) {
        int s0 = csr_src[e], s1 = csr_src[e + 1], s2 = csr_src[e + 2], s3 = csr_src[e + 3];
        ushort4 v0 = *(const ushort4*)(Hl + (size_t)s0 * F);
        ushort4 v1 = *(const ushort4*)(Hl + (size_t)s1 * F);
        ushort4 v2 = *(const ushort4*)(Hl + (size_t)s2 * F);
        ushort4 v3 = *(const ushort4*)(Hl + (size_t)s3 * F);
        acc0 += bf2f(v0.x) + bf2f(v1.x) + bf2f(v2.x) + bf2f(v3.x);
        acc1 += bf2f(v0.y) + bf2f(v1.y) + bf2f(v2.y) + bf2f(v3.y);
        acc2 += bf2f(v0.z) + bf2f(v1.z) + bf2f(v2.z) + bf2f(v3.z);
        acc3 += bf2f(v0.w) + bf2f(v1.w) + bf2f(v2.w) + bf2f(v3.w);
    }
    for (; e < e1; ++e) {
        int s = csr_src[e];
        ushort4 v = *(const ushort4*)(Hl + (size_t)s * F);
        acc0 += bf2f(v.x); acc1 += bf2f(v.y); acc2 += bf2f(v.z); acc3 += bf2f(v.w);
    }

    float nd = norm_dst[node];
    float4 o;
    o.x = fmaf(acc0, nd, bias[f0 + 0]);
    o.y = fmaf(acc1, nd, bias[f0 + 1]);
    o.z = fmaf(acc2, nd, bias[f0 + 2]);
    o.w = fmaf(acc3, nd, bias[f0 + 3]);
    *(float4*)(out + (size_t)node * F + f0) = o;
}

// ---------------- launch ----------------
extern "C" void kernel_launch(void* const* d_in, const int* in_sizes, int n_in,
                              void* d_out, int out_size, void* d_ws, size_t ws_size,
                              hipStream_t stream) {
    const float* x   = (const float*)d_in[0];
    const int*   src = (const int*)d_in[1];
    const int*   dst = (const int*)d_in[2];
    const float* W1  = (const float*)d_in[3];
    const float* b1  = (const float*)d_in[4];
    const float* W2  = (const float*)d_in[5];
    const float* b2  = (const float*)d_in[6];
    float* out = (float*)d_out;

    char* ws = (char*)d_ws;
    size_t off = 0;
    auto alloc = [&](size_t bytes) {
        char* p = ws + off;
        off += (bytes + 255) & ~(size_t)255;
        return p;
    };
    float* norm_src  = (float*)alloc(NNODES * 4);
    float* norm_dst  = (float*)alloc(NNODES * 4);
    int*   deg_out   = (int*)alloc(NNODES * 4);
    int*   deg_in    = (int*)alloc(NNODES * 4);
    int*   row_ptr   = (int*)alloc((NNODES + 256) * 4);
    int*   cursor    = (int*)alloc(NNODES * 4);
    int*   blockSums = (int*)alloc(256 * 4);
    int*   csr_src   = (int*)alloc(NEDGES * 4);
    unsigned short* h  = (unsigned short*)alloc((size_t)NNODES * FH * 2);  // bf16, reused for h2
    unsigned short* h1 = (unsigned short*)alloc((size_t)NNODES * FH * 2);  // bf16 (post-relu)
    unsigned short* h2 = h;                                                // [NNODES, FOUT] bf16

    const int NB_N = (NNODES + 255) / 256;   // 196
    const int NB_E = (NEDGES + 255) / 256;   // 3125

    hipMemsetAsync(deg_out, 0, NNODES * 4, stream);
    hipMemsetAsync(deg_in, 0, NNODES * 4, stream);

    deg_kernel<<<NB_E, 256, 0, stream>>>(src, dst, deg_out, deg_in);
    norm_kernel<<<NB_N, 256, 0, stream>>>(deg_out, deg_in, norm_src, norm_dst);
    scan1<<<NB_N, 256, 0, stream>>>(deg_in, row_ptr, blockSums);
    scan2<<<1, 256, 0, stream>>>(blockSums, NB_N);
    scan3<<<NB_N, 256, 0, stream>>>(row_ptr, blockSums, cursor);
    fill_csr<<<NB_E, 256, 0, stream>>>(src, dst, cursor, csr_src);

    // layer 1: h = bf16((x * norm_src) @ W1) ; h1 = bf16(relu(agg(h) * norm_dst + b1))
    gemm_norm<float><<<dim3(FH / 64, (NNODES + 63) / 64), 256, 0, stream>>>(x, W1, norm_src, h, FH);
    agg1_kernel<<<(NNODES + 3) / 4, 256, 0, stream>>>(h, row_ptr, csr_src, norm_dst, b1, h1);

    // layer 2: h2 = bf16((h1 * norm_src) @ W2) ; out = agg(h2) * norm_dst + b2  (fp32 out)
    gemm_norm<unsigned short><<<dim3(FOUT / 64, (NNODES + 63) / 64), 256, 0, stream>>>(h1, W2, norm_src, h2, FOUT);
    agg2_kernel<<<(NNODES + 7) / 8, 256, 0, stream>>>(h2, row_ptr, csr_src, norm_dst, b2, out);
}

// Round 5
// 356.320 us; speedup vs baseline: 1.4964x; 1.2475x over previous
//
#include <hip/hip_runtime.h>

#define NNODES 50000
#define MPAD   50048    // padded to multiple of 128 for MFMA tiles
#define NEDGES 800000
#define KDIM   256      // in/hidden feature dim (GEMM K)
#define FH     256      // hidden feats
#define FOUT   128      // out feats

typedef __bf16 bf16x8 __attribute__((ext_vector_type(8)));
typedef float floatx4 __attribute__((ext_vector_type(4)));

// ---------------- bf16 helpers (RNE) ----------------
__device__ __forceinline__ float bf2f(unsigned short u) {
    union { unsigned int i; float f; } v;
    v.i = ((unsigned int)u) << 16;
    return v.f;
}
__device__ __forceinline__ unsigned short f2bf(float f) {
    union { float f; unsigned int i; } v;
    v.f = f;
    unsigned int r = v.i + 0x7FFFu + ((v.i >> 16) & 1u);
    return (unsigned short)(r >> 16);
}

// ---------------- degree + norm ----------------
__global__ __launch_bounds__(256) void deg_kernel(const int* __restrict__ src,
                                                  const int* __restrict__ dst,
                                                  int* __restrict__ deg_out,
                                                  int* __restrict__ deg_in) {
    int e = blockIdx.x * 256 + threadIdx.x;
    if (e < NEDGES) {
        atomicAdd(&deg_out[src[e]], 1);
        atomicAdd(&deg_in[dst[e]], 1);
    }
}

__global__ __launch_bounds__(256) void norm_kernel(const int* __restrict__ deg_out,
                                                   const int* __restrict__ deg_in,
                                                   float* __restrict__ norm_src,
                                                   float* __restrict__ norm_dst) {
    int i = blockIdx.x * 256 + threadIdx.x;
    if (i < NNODES) {
        int dso = deg_out[i]; if (dso < 1) dso = 1;
        int dsi = deg_in[i];  if (dsi < 1) dsi = 1;
        norm_src[i] = 1.0f / sqrtf((float)dso);
        norm_dst[i] = 1.0f / sqrtf((float)dsi);
    }
}

// ---------------- exclusive scan of deg_in -> row_ptr ----------------
__global__ __launch_bounds__(256) void scan1(const int* __restrict__ deg_in,
                                             int* __restrict__ excl,
                                             int* __restrict__ blockSums) {
    __shared__ int s[256];
    int tid = threadIdx.x;
    int i = blockIdx.x * 256 + tid;
    int v = (i < NNODES) ? deg_in[i] : 0;
    s[tid] = v;
    __syncthreads();
    for (int off = 1; off < 256; off <<= 1) {
        int t = (tid >= off) ? s[tid - off] : 0;
        __syncthreads();
        s[tid] += t;
        __syncthreads();
    }
    excl[i] = s[tid] - v;
    if (tid == 255) blockSums[blockIdx.x] = s[255];
}

__global__ __launch_bounds__(256) void scan2(int* __restrict__ blockSums, int nblocks) {
    __shared__ int s[256];
    int tid = threadIdx.x;
    int v = (tid < nblocks) ? blockSums[tid] : 0;
    s[tid] = v;
    __syncthreads();
    for (int off = 1; off < 256; off <<= 1) {
        int t = (tid >= off) ? s[tid - off] : 0;
        __syncthreads();
        s[tid] += t;
        __syncthreads();
    }
    if (tid < nblocks) blockSums[tid] = s[tid] - v;
}

__global__ __launch_bounds__(256) void scan3(int* __restrict__ row_ptr,
                                             const int* __restrict__ blockSums,
                                             int* __restrict__ cursor) {
    int i = blockIdx.x * 256 + threadIdx.x;
    if (i < NNODES) {
        int r = row_ptr[i] + blockSums[blockIdx.x];
        row_ptr[i] = r;
        cursor[i] = r;
    }
    if (i == 0) row_ptr[NNODES] = NEDGES;
}

__global__ __launch_bounds__(256) void fill_csr(const int* __restrict__ src,
                                                const int* __restrict__ dst,
                                                int* __restrict__ cursor,
                                                int* __restrict__ csr_src) {
    int e = blockIdx.x * 256 + threadIdx.x;
    if (e < NEDGES) {
        int d = dst[e];
        int p = atomicAdd(&cursor[d], 1);
        csr_src[p] = src[e];
    }
}

// ---------------- cast x*norm -> bf16, zero pad rows ----------------
__global__ __launch_bounds__(256) void cast_x(const float* __restrict__ x,
                                              const float* __restrict__ norm_src,
                                              unsigned short* __restrict__ xb) {
    int idx = blockIdx.x * 256 + threadIdx.x;       // 4-elem group
    const int total = MPAD * (KDIM / 4);
    if (idx >= total) return;
    int n = idx >> 6;            // KDIM/4 = 64 groups per row
    int c = (idx & 63) << 2;
    ushort4 o = {0, 0, 0, 0};
    if (n < NNODES) {
        float s = norm_src[n];
        float4 v = *(const float4*)(x + (size_t)n * KDIM + c);
        o.x = f2bf(v.x * s); o.y = f2bf(v.y * s); o.z = f2bf(v.z * s); o.w = f2bf(v.w * s);
    }
    *(ushort4*)(xb + (size_t)n * KDIM + c) = o;
}

// ---------------- W[K][N] -> Wt[N][K] bf16 (LDS 32x32 tile transpose) ----------------
__global__ __launch_bounds__(256) void cast_wt(const float* __restrict__ W,
                                               unsigned short* __restrict__ Wt,
                                               int K, int N) {
    __shared__ float tile[32][33];
    int kt = blockIdx.x * 32;
    int nt = blockIdx.y * 32;
    int tx = threadIdx.x & 31;
    int ty = threadIdx.x >> 5;  // 0..7
    for (int r = ty; r < 32; r += 8)
        tile[r][tx] = W[(size_t)(kt + r) * N + nt + tx];
    __syncthreads();
    for (int r = ty; r < 32; r += 8)
        Wt[(size_t)(nt + r) * K + kt + tx] = f2bf(tile[tx][r]);
}

// ---------------- bf16 MFMA GEMM: C[M,N] = A[M,256] @ Bt[N,256]^T ----------------
// 128x128 tile, BK=32, 256 threads = 4 waves, each wave 64x64 via 4x4 of 16x16x32 MFMA.
// Layout facts (HW-verified, and re-confirmed by the R4 runtime probe which matched
// this hardcoded epilogue bit-exactly): A-frag m=lane&15, k=(lane>>4)*8+j;
// C/D col=lane&15, row=(lane>>4)*4+reg.
__global__ __launch_bounds__(256) void gemm_mfma(const unsigned short* __restrict__ A,   // [MPAD][256] bf16
                                                 const unsigned short* __restrict__ Bt,  // [N][256] bf16
                                                 unsigned short* __restrict__ C,         // [NNODES][N] bf16
                                                 int N) {
    __shared__ __align__(16) unsigned short As[128][32];   // 8 KB
    __shared__ __align__(16) unsigned short Bs[128][32];   // 8 KB  (Bs[n][k])

    const int tid = threadIdx.x;
    const int lane = tid & 63;
    const int wave = tid >> 6;
    const int wm = wave & 1, wn = wave >> 1;
    const int m0 = blockIdx.x * 128;
    const int n0 = blockIdx.y * 128;

    const int srow = tid >> 2;           // 0..63
    const int sk = (tid & 3) << 3;       // 0,8,16,24

    const unsigned short* Ag = A + (size_t)(m0 + srow) * KDIM + sk;
    const unsigned short* Bg = Bt + (size_t)(n0 + srow) * KDIM + sk;

    floatx4 acc[4][4] = {};

    const int ar = wm * 64 + (lane & 15);
    const int br = wn * 64 + (lane & 15);
    const int fk = (lane >> 4) << 3;     // 0,8,16,24

    for (int kk = 0; kk < KDIM; kk += 32) {
        uint4 a0 = *(const uint4*)(Ag + kk);
        uint4 a1 = *(const uint4*)(Ag + (size_t)64 * KDIM + kk);
        uint4 b0 = *(const uint4*)(Bg + kk);
        uint4 b1 = *(const uint4*)(Bg + (size_t)64 * KDIM + kk);
        __syncthreads();
        *(uint4*)&As[srow][sk] = a0;
        *(uint4*)&As[srow + 64][sk] = a1;
        *(uint4*)&Bs[srow][sk] = b0;
        *(uint4*)&Bs[srow + 64][sk] = b1;
        __syncthreads();

        bf16x8 af[4], bfr[4];
#pragma unroll
        for (int i = 0; i < 4; ++i) {
            af[i]  = *(const bf16x8*)&As[ar + i * 16][fk];
            bfr[i] = *(const bf16x8*)&Bs[br + i * 16][fk];
        }
#pragma unroll
        for (int i = 0; i < 4; ++i)
#pragma unroll
            for (int j = 0; j < 4; ++j)
                acc[i][j] = __builtin_amdgcn_mfma_f32_16x16x32_bf16(af[i], bfr[j], acc[i][j], 0, 0, 0);
    }

    // C/D layout: col = lane&15, row = (lane>>4)*4 + reg
    const int rb = (lane >> 4) << 2;
    const int cc = lane & 15;
#pragma unroll
    for (int i = 0; i < 4; ++i) {
        int mb = m0 + wm * 64 + i * 16 + rb;
#pragma unroll
        for (int j = 0; j < 4; ++j) {
            int col = n0 + wn * 64 + j * 16 + cc;
#pragma unroll
            for (int r = 0; r < 4; ++r) {
                int m = mb + r;
                if (m < NNODES)
                    C[(size_t)m * N + col] = f2bf(acc[i][j][r]);
            }
        }
    }
}

// ---------------- agg layer 1: bf16 in (F=256), bf16 out.
// h1[node] = relu(agg * norm_dst + b1) * norm_src   <- norm_src pre-scales gemm2's A
// (relu commutes with the positive norm_src factor; this was the R3/R4 bug: the
//  reference's second GraphConv scales its input by norm_src before @W2.)
__global__ __launch_bounds__(256) void agg1_kernel(const unsigned short* __restrict__ H,
                                                   const int* __restrict__ row_ptr,
                                                   const int* __restrict__ csr_src,
                                                   const float* __restrict__ norm_dst,
                                                   const float* __restrict__ norm_src,
                                                   const float* __restrict__ bias,
                                                   unsigned short* __restrict__ out) {
    const int F = 256;
    int node = blockIdx.x * 4 + (threadIdx.x >> 6);
    if (node >= NNODES) return;
    int lane = threadIdx.x & 63;
    int f0 = lane * 4;
    int e0 = row_ptr[node];
    int e1 = row_ptr[node + 1];

    float acc0 = 0.f, acc1 = 0.f, acc2 = 0.f, acc3 = 0.f;
    const unsigned short* Hl = H + f0;

    int e = e0;
    for (; e + 3 < e1; e += 4) {
        int s0 = csr_src[e], s1 = csr_src[e + 1], s2 = csr_src[e + 2], s3 = csr_src[e + 3];
        ushort4 v0 = *(const ushort4*)(Hl + (size_t)s0 * F);
        ushort4 v1 = *(const ushort4*)(Hl + (size_t)s1 * F);
        ushort4 v2 = *(const ushort4*)(Hl + (size_t)s2 * F);
        ushort4 v3 = *(const ushort4*)(Hl + (size_t)s3 * F);
        acc0 += bf2f(v0.x) + bf2f(v1.x) + bf2f(v2.x) + bf2f(v3.x);
        acc1 += bf2f(v0.y) + bf2f(v1.y) + bf2f(v2.y) + bf2f(v3.y);
        acc2 += bf2f(v0.z) + bf2f(v1.z) + bf2f(v2.z) + bf2f(v3.z);
        acc3 += bf2f(v0.w) + bf2f(v1.w) + bf2f(v2.w) + bf2f(v3.w);
    }
    for (; e < e1; ++e) {
        int s = csr_src[e];
        ushort4 v = *(const ushort4*)(Hl + (size_t)s * F);
        acc0 += bf2f(v.x); acc1 += bf2f(v.y); acc2 += bf2f(v.z); acc3 += bf2f(v.w);
    }

    float nd = norm_dst[node];
    float ns = norm_src[node];
    float o0 = fmaxf(fmaf(acc0, nd, bias[f0 + 0]), 0.0f) * ns;
    float o1 = fmaxf(fmaf(acc1, nd, bias[f0 + 1]), 0.0f) * ns;
    float o2 = fmaxf(fmaf(acc2, nd, bias[f0 + 2]), 0.0f) * ns;
    float o3 = fmaxf(fmaf(acc3, nd, bias[f0 + 3]), 0.0f) * ns;
    ushort4 o;
    o.x = f2bf(o0); o.y = f2bf(o1); o.z = f2bf(o2); o.w = f2bf(o3);
    *(ushort4*)(out + (size_t)node * F + f0) = o;
}

// ---------------- agg layer 2: bf16 in (F=128), fp32 out, no relu. ----------------
__global__ __launch_bounds__(256) void agg2_kernel(const unsigned short* __restrict__ H,
                                                   const int* __restrict__ row_ptr,
                                                   const int* __restrict__ csr_src,
                                                   const float* __restrict__ norm_dst,
                                                   const float* __restrict__ bias,
                                                   float* __restrict__ out) {
    const int F = 128;
    int node = blockIdx.x * 8 + (threadIdx.x >> 5);
    if (node >= NNODES) return;
    int lane = threadIdx.x & 31;
    int f0 = lane * 4;
    int e0 = row_ptr[node];
    int e1 = row_ptr[node + 1];

    float acc0 = 0.f, acc1 = 0.f, acc2 = 0.f, acc3 = 0.f;
    const unsigned short* Hl = H + f0;

    int e = e0;
    for (; e + 3 < e1; e += 4) {
        int s0 = csr_src[e], s1 = csr_src[e + 1], s2 = csr_src[e + 2], s3 = csr_src[e + 3];
        ushort4 v0 = *(const ushort4*)(Hl + (size_t)s0 * F);
        ushort4 v1 = *(const ushort4*)(Hl + (size_t)s1 * F);
        ushort4 v2 = *(const ushort4*)(Hl + (size_t)s2 * F);
        ushort4 v3 = *(const ushort4*)(Hl + (size_t)s3 * F);
        acc0 += bf2f(v0.x) + bf2f(v1.x) + bf2f(v2.x) + bf2f(v3.x);
        acc1 += bf2f(v0.y) + bf2f(v1.y) + bf2f(v2.y) + bf2f(v3.y);
        acc2 += bf2f(v0.z) + bf2f(v1.z) + bf2f(v2.z) + bf2f(v3.z);
        acc3 += bf2f(v0.w) + bf2f(v1.w) + bf2f(v2.w) + bf2f(v3.w);
    }
    for (; e < e1; ++e) {
        int s = csr_src[e];
        ushort4 v = *(const ushort4*)(Hl + (size_t)s * F);
        acc0 += bf2f(v.x); acc1 += bf2f(v.y); acc2 += bf2f(v.z); acc3 += bf2f(v.w);
    }

    float nd = norm_dst[node];
    float4 o;
    o.x = fmaf(acc0, nd, bias[f0 + 0]);
    o.y = fmaf(acc1, nd, bias[f0 + 1]);
    o.z = fmaf(acc2, nd, bias[f0 + 2]);
    o.w = fmaf(acc3, nd, bias[f0 + 3]);
    *(float4*)(out + (size_t)node * F + f0) = o;
}

// ---------------- launch ----------------
extern "C" void kernel_launch(void* const* d_in, const int* in_sizes, int n_in,
                              void* d_out, int out_size, void* d_ws, size_t ws_size,
                              hipStream_t stream) {
    const float* x   = (const float*)d_in[0];
    const int*   src = (const int*)d_in[1];
    const int*   dst = (const int*)d_in[2];
    const float* W1  = (const float*)d_in[3];
    const float* b1  = (const float*)d_in[4];
    const float* W2  = (const float*)d_in[5];
    const float* b2  = (const float*)d_in[6];
    float* out = (float*)d_out;

    char* ws = (char*)d_ws;
    size_t off = 0;
    auto alloc = [&](size_t bytes) {
        char* p = ws + off;
        off += (bytes + 255) & ~(size_t)255;
        return p;
    };
    float* norm_src  = (float*)alloc(NNODES * 4);
    float* norm_dst  = (float*)alloc(NNODES * 4);
    int*   deg_out   = (int*)alloc(NNODES * 4);
    int*   deg_in    = (int*)alloc(NNODES * 4);
    int*   row_ptr   = (int*)alloc((NNODES + 256) * 4);
    int*   cursor    = (int*)alloc(NNODES * 4);
    int*   blockSums = (int*)alloc(256 * 4);
    int*   csr_src   = (int*)alloc(NEDGES * 4);
    unsigned short* xb  = (unsigned short*)alloc((size_t)MPAD * KDIM * 2);  // bf16 x*norm_src
    unsigned short* h   = (unsigned short*)alloc((size_t)NNODES * FH * 2);  // gemm1 out, reused as h2
    unsigned short* h1  = (unsigned short*)alloc((size_t)MPAD * FH * 2);    // agg1 out * norm_src (padded)
    unsigned short* Wt1 = (unsigned short*)alloc((size_t)FH * KDIM * 2);    // [256][256]
    unsigned short* Wt2 = (unsigned short*)alloc((size_t)FOUT * KDIM * 2);  // [128][256]
    unsigned short* h2  = h;                                                // [NNODES][FOUT]

    const int NB_N = (NNODES + 255) / 256;
    const int NB_E = (NEDGES + 255) / 256;

    hipMemsetAsync(deg_out, 0, NNODES * 4, stream);
    hipMemsetAsync(deg_in, 0, NNODES * 4, stream);
    // zero h1's pad rows so gemm2's unguarded A-tile loads read zeros
    hipMemsetAsync(h1 + (size_t)NNODES * FH, 0, (size_t)(MPAD - NNODES) * FH * 2, stream);

    deg_kernel<<<NB_E, 256, 0, stream>>>(src, dst, deg_out, deg_in);
    norm_kernel<<<NB_N, 256, 0, stream>>>(deg_out, deg_in, norm_src, norm_dst);

    cast_x<<<(MPAD * (KDIM / 4) + 255) / 256, 256, 0, stream>>>(x, norm_src, xb);
    cast_wt<<<dim3(KDIM / 32, FH / 32), 256, 0, stream>>>(W1, Wt1, KDIM, FH);
    cast_wt<<<dim3(KDIM / 32, FOUT / 32), 256, 0, stream>>>(W2, Wt2, KDIM, FOUT);

    scan1<<<NB_N, 256, 0, stream>>>(deg_in, row_ptr, blockSums);
    scan2<<<1, 256, 0, stream>>>(blockSums, NB_N);
    scan3<<<NB_N, 256, 0, stream>>>(row_ptr, blockSums, cursor);
    fill_csr<<<NB_E, 256, 0, stream>>>(src, dst, cursor, csr_src);

    // layer 1: h = bf16(xb @ W1) ; h1 = bf16(relu(agg(h)*norm_dst + b1) * norm_src)
    gemm_mfma<<<dim3(MPAD / 128, FH / 128), 256, 0, stream>>>(xb, Wt1, h, FH);
    agg1_kernel<<<(NNODES + 3) / 4, 256, 0, stream>>>(h, row_ptr, csr_src, norm_dst, norm_src, b1, h1);

    // layer 2: h2 = bf16(h1 @ W2) ; out = agg(h2) * norm_dst + b2  (fp32 out)
    gemm_mfma<<<dim3(MPAD / 128, FOUT / 128), 256, 0, stream>>>(h1, Wt2, h2, FOUT);
    agg2_kernel<<<(NNODES + 7) / 8, 256, 0, stream>>>(h2, row_ptr, csr_src, norm_dst, b2, out);
}

// Round 6
// 346.294 us; speedup vs baseline: 1.5397x; 1.0290x over previous
//
#include <hip/hip_runtime.h>

#define NNODES 50000
#define MPAD   50048    // padded to multiple of 128 for MFMA tiles
#define NEDGES 800000
#define KDIM   256      // in/hidden feature dim (GEMM K)
#define FH     256      // hidden feats
#define FOUT   128      // out feats
#define CPAD   16       // counter padding: 16 ints = 64B = one cache line per counter

typedef __bf16 bf16x8 __attribute__((ext_vector_type(8)));
typedef float floatx4 __attribute__((ext_vector_type(4)));

// ---------------- bf16 helpers (RNE) ----------------
__device__ __forceinline__ float bf2f(unsigned short u) {
    union { unsigned int i; float f; } v;
    v.i = ((unsigned int)u) << 16;
    return v.f;
}
__device__ __forceinline__ unsigned short f2bf(float f) {
    union { float f; unsigned int i; } v;
    v.f = f;
    unsigned int r = v.i + 0x7FFFu + ((v.i >> 16) & 1u);
    return (unsigned short)(r >> 16);
}

// ---------------- degree (padded counters, 4 edges/thread) ----------------
__global__ __launch_bounds__(256) void deg_kernel(const int* __restrict__ src,
                                                  const int* __restrict__ dst,
                                                  int* __restrict__ deg_out,
                                                  int* __restrict__ deg_in) {
    int g = blockIdx.x * 256 + threadIdx.x;          // group of 4 edges
    if (g >= NEDGES / 4) return;
    uint4 s4 = *(const uint4*)(src + g * 4);
    uint4 d4 = *(const uint4*)(dst + g * 4);
    atomicAdd(&deg_out[s4.x * CPAD], 1);
    atomicAdd(&deg_out[s4.y * CPAD], 1);
    atomicAdd(&deg_out[s4.z * CPAD], 1);
    atomicAdd(&deg_out[s4.w * CPAD], 1);
    atomicAdd(&deg_in[d4.x * CPAD], 1);
    atomicAdd(&deg_in[d4.y * CPAD], 1);
    atomicAdd(&deg_in[d4.z * CPAD], 1);
    atomicAdd(&deg_in[d4.w * CPAD], 1);
}

// ---------------- fused: norms + block-local exclusive scan of deg_in ----------------
__global__ __launch_bounds__(256) void scan1f(const int* __restrict__ deg_in,
                                              const int* __restrict__ deg_out,
                                              float* __restrict__ norm_src,
                                              float* __restrict__ norm_dst,
                                              int* __restrict__ excl,   // row_ptr temp
                                              int* __restrict__ blockSums) {
    __shared__ int s[256];
    int tid = threadIdx.x;
    int i = blockIdx.x * 256 + tid;
    int v = 0;
    if (i < NNODES) {
        v = deg_in[i * CPAD];
        int doo = deg_out[i * CPAD]; if (doo < 1) doo = 1;
        int dii = v; if (dii < 1) dii = 1;
        norm_src[i] = 1.0f / sqrtf((float)doo);
        norm_dst[i] = 1.0f / sqrtf((float)dii);
    }
    s[tid] = v;
    __syncthreads();
    for (int off = 1; off < 256; off <<= 1) {
        int t = (tid >= off) ? s[tid - off] : 0;
        __syncthreads();
        s[tid] += t;
        __syncthreads();
    }
    excl[i] = s[tid] - v;
    if (tid == 255) blockSums[blockIdx.x] = s[255];
}

__global__ __launch_bounds__(256) void scan2(int* __restrict__ blockSums, int nblocks) {
    __shared__ int s[256];
    int tid = threadIdx.x;
    int v = (tid < nblocks) ? blockSums[tid] : 0;
    s[tid] = v;
    __syncthreads();
    for (int off = 1; off < 256; off <<= 1) {
        int t = (tid >= off) ? s[tid - off] : 0;
        __syncthreads();
        s[tid] += t;
        __syncthreads();
    }
    if (tid < nblocks) blockSums[tid] = s[tid] - v;
}

__global__ __launch_bounds__(256) void scan3(int* __restrict__ row_ptr,
                                             const int* __restrict__ blockSums,
                                             int* __restrict__ cursor) {
    int i = blockIdx.x * 256 + threadIdx.x;
    if (i < NNODES) {
        int r = row_ptr[i] + blockSums[blockIdx.x];
        row_ptr[i] = r;
        cursor[i * CPAD] = r;
    }
    if (i == 0) row_ptr[NNODES] = NEDGES;
}

__global__ __launch_bounds__(256) void fill_csr(const int* __restrict__ src,
                                                const int* __restrict__ dst,
                                                int* __restrict__ cursor,
                                                int* __restrict__ csr_src) {
    int e = blockIdx.x * 256 + threadIdx.x;
    if (e < NEDGES) {
        int d = dst[e];
        int p = atomicAdd(&cursor[d * CPAD], 1);
        csr_src[p] = src[e];
    }
}

// ---------------- W1,W2 [K][N] -> Wt [N][K] bf16 (one kernel, LDS 32x32 transpose) ----------------
__global__ __launch_bounds__(256) void cast_wt_both(const float* __restrict__ W1,
                                                    unsigned short* __restrict__ Wt1,
                                                    const float* __restrict__ W2,
                                                    unsigned short* __restrict__ Wt2) {
    __shared__ float tile[32][33];
    int b = blockIdx.x;
    const float* W; unsigned short* Wt; int N;
    if (b < 64) { W = W1; Wt = Wt1; N = FH; }                 // 8 (k) x 8 (n) tiles
    else        { b -= 64; W = W2; Wt = Wt2; N = FOUT; }      // 8 (k) x 4 (n) tiles
    int kt = (b & 7) * 32;
    int nt = (b >> 3) * 32;
    int tx = threadIdx.x & 31;
    int ty = threadIdx.x >> 5;  // 0..7
    for (int r = ty; r < 32; r += 8)
        tile[r][tx] = W[(size_t)(kt + r) * N + nt + tx];
    __syncthreads();
    for (int r = ty; r < 32; r += 8)
        Wt[(size_t)(nt + r) * KDIM + kt + tx] = f2bf(tile[tx][r]);
}

// ---------------- A-staging loaders (8 bf16 = 16B, packed in uint4) ----------------
__device__ __forceinline__ uint4 stage_a8(const float* A, int row, int k, float scale, bool valid) {
    if (!valid) return make_uint4(0u, 0u, 0u, 0u);
    const float* p = A + (size_t)row * KDIM + k;
    float4 v0 = *(const float4*)p;
    float4 v1 = *(const float4*)(p + 4);
    union { uint4 u; unsigned short s[8]; } r;
    r.s[0] = f2bf(v0.x * scale); r.s[1] = f2bf(v0.y * scale);
    r.s[2] = f2bf(v0.z * scale); r.s[3] = f2bf(v0.w * scale);
    r.s[4] = f2bf(v1.x * scale); r.s[5] = f2bf(v1.y * scale);
    r.s[6] = f2bf(v1.z * scale); r.s[7] = f2bf(v1.w * scale);
    return r.u;
}
__device__ __forceinline__ uint4 stage_a8(const unsigned short* A, int row, int k, float, bool) {
    return *(const uint4*)(A + (size_t)row * KDIM + k);
}

// ---------------- bf16 MFMA GEMM: C[M,N] = (A[M,256] * norm?) @ Bt[N,256]^T ----------------
// 128x128 tile, BK=32, 256 threads = 4 waves, each wave 64x64 via 4x4 of 16x16x32 MFMA.
// Layout (HW-verified; R4 probe matched bit-exact): A-frag m=lane&15, k=(lane>>4)*8+j;
// C/D col=lane&15, row=(lane>>4)*4+reg.
// SCALE=true: A is fp32, row-scaled by norm[] and cast to bf16 in-register (fuses old cast_x).
template <typename TA, bool SCALE>
__global__ __launch_bounds__(256) void gemm_mfma(const TA* __restrict__ A,
                                                 const unsigned short* __restrict__ Bt,  // [N][256] bf16
                                                 const float* __restrict__ norm,
                                                 unsigned short* __restrict__ C,         // [NNODES][N] bf16
                                                 int N) {
    __shared__ __align__(16) unsigned short As[128][32];   // 8 KB
    __shared__ __align__(16) unsigned short Bs[128][32];   // 8 KB  (Bs[n][k])

    const int tid = threadIdx.x;
    const int lane = tid & 63;
    const int wave = tid >> 6;
    const int wm = wave & 1, wn = wave >> 1;
    const int m0 = blockIdx.x * 128;
    const int n0 = blockIdx.y * 128;

    const int srow = tid >> 2;           // 0..63
    const int sk = (tid & 3) << 3;       // 0,8,16,24

    const int r0 = m0 + srow;
    const int r1 = r0 + 64;
    bool va0 = true, va1 = true;
    float sc0 = 0.f, sc1 = 0.f;
    if (SCALE) {
        va0 = (r0 < NNODES); va1 = (r1 < NNODES);
        sc0 = va0 ? norm[r0] : 0.f;
        sc1 = va1 ? norm[r1] : 0.f;
    }

    const unsigned short* Bg = Bt + (size_t)(n0 + srow) * KDIM + sk;

    floatx4 acc[4][4] = {};

    const int ar = wm * 64 + (lane & 15);
    const int br = wn * 64 + (lane & 15);
    const int fk = (lane >> 4) << 3;     // 0,8,16,24

    for (int kk = 0; kk < KDIM; kk += 32) {
        uint4 a0 = stage_a8(A, va0 ? r0 : 0, kk + sk, sc0, va0);
        uint4 a1 = stage_a8(A, va1 ? r1 : 0, kk + sk, sc1, va1);
        uint4 b0 = *(const uint4*)(Bg + kk);
        uint4 b1 = *(const uint4*)(Bg + (size_t)64 * KDIM + kk);
        __syncthreads();
        *(uint4*)&As[srow][sk] = a0;
        *(uint4*)&As[srow + 64][sk] = a1;
        *(uint4*)&Bs[srow][sk] = b0;
        *(uint4*)&Bs[srow + 64][sk] = b1;
        __syncthreads();

        bf16x8 af[4], bfr[4];
#pragma unroll
        for (int i = 0; i < 4; ++i) {
            af[i]  = *(const bf16x8*)&As[ar + i * 16][fk];
            bfr[i] = *(const bf16x8*)&Bs[br + i * 16][fk];
        }
#pragma unroll
        for (int i = 0; i < 4; ++i)
#pragma unroll
            for (int j = 0; j < 4; ++j)
                acc[i][j] = __builtin_amdgcn_mfma_f32_16x16x32_bf16(af[i], bfr[j], acc[i][j], 0, 0, 0);
    }

    const int rb = (lane >> 4) << 2;
    const int cc = lane & 15;
#pragma unroll
    for (int i = 0; i < 4; ++i) {
        int mb = m0 + wm * 64 + i * 16 + rb;
#pragma unroll
        for (int j = 0; j < 4; ++j) {
            int col = n0 + wn * 64 + j * 16 + cc;
#pragma unroll
            for (int r = 0; r < 4; ++r) {
                int m = mb + r;
                if (m < NNODES)
                    C[(size_t)m * N + col] = f2bf(acc[i][j][r]);
            }
        }
    }
}

// ---------------- agg layer 1: bf16 in (F=256), bf16 out.
// h1[node] = relu(agg * norm_dst + b1) * norm_src  (norm_src pre-scales gemm2's A).
// Grid extends to MPAD/4: pad nodes write zeros (replaces the h1-pad memset).
__global__ __launch_bounds__(256) void agg1_kernel(const unsigned short* __restrict__ H,
                                                   const int* __restrict__ row_ptr,
                                                   const int* __restrict__ csr_src,
                                                   const float* __restrict__ norm_dst,
                                                   const float* __restrict__ norm_src,
                                                   const float* __restrict__ bias,
                                                   unsigned short* __restrict__ out) {
    const int F = 256;
    int node = blockIdx.x * 4 + (threadIdx.x >> 6);
    int lane = threadIdx.x & 63;
    int f0 = lane * 4;
    if (node >= NNODES) {
        if (node < MPAD) {
            ushort4 z = {0, 0, 0, 0};
            *(ushort4*)(out + (size_t)node * F + f0) = z;
        }
        return;
    }
    int e0 = row_ptr[node];
    int e1 = row_ptr[node + 1];

    float acc0 = 0.f, acc1 = 0.f, acc2 = 0.f, acc3 = 0.f;
    const unsigned short* Hl = H + f0;

    int e = e0;
    for (; e + 3 < e1; e += 4) {
        int s0 = csr_src[e], s1 = csr_src[e + 1], s2 = csr_src[e + 2], s3 = csr_src[e + 3];
        ushort4 v0 = *(const ushort4*)(Hl + (size_t)s0 * F);
        ushort4 v1 = *(const ushort4*)(Hl + (size_t)s1 * F);
        ushort4 v2 = *(const ushort4*)(Hl + (size_t)s2 * F);
        ushort4 v3 = *(const ushort4*)(Hl + (size_t)s3 * F);
        acc0 += bf2f(v0.x) + bf2f(v1.x) + bf2f(v2.x) + bf2f(v3.x);
        acc1 += bf2f(v0.y) + bf2f(v1.y) + bf2f(v2.y) + bf2f(v3.y);
        acc2 += bf2f(v0.z) + bf2f(v1.z) + bf2f(v2.z) + bf2f(v3.z);
        acc3 += bf2f(v0.w) + bf2f(v1.w) + bf2f(v2.w) + bf2f(v3.w);
    }
    for (; e < e1; ++e) {
        int s = csr_src[e];
        ushort4 v = *(const ushort4*)(Hl + (size_t)s * F);
        acc0 += bf2f(v.x); acc1 += bf2f(v.y); acc2 += bf2f(v.z); acc3 += bf2f(v.w);
    }

    float nd = norm_dst[node];
    float ns = norm_src[node];
    float o0 = fmaxf(fmaf(acc0, nd, bias[f0 + 0]), 0.0f) * ns;
    float o1 = fmaxf(fmaf(acc1, nd, bias[f0 + 1]), 0.0f) * ns;
    float o2 = fmaxf(fmaf(acc2, nd, bias[f0 + 2]), 0.0f) * ns;
    float o3 = fmaxf(fmaf(acc3, nd, bias[f0 + 3]), 0.0f) * ns;
    ushort4 o;
    o.x = f2bf(o0); o.y = f2bf(o1); o.z = f2bf(o2); o.w = f2bf(o3);
    *(ushort4*)(out + (size_t)node * F + f0) = o;
}

// ---------------- agg layer 2: bf16 in (F=128), fp32 out, no relu. ----------------
__global__ __launch_bounds__(256) void agg2_kernel(const unsigned short* __restrict__ H,
                                                   const int* __restrict__ row_ptr,
                                                   const int* __restrict__ csr_src,
                                                   const float* __restrict__ norm_dst,
                                                   const float* __restrict__ bias,
                                                   float* __restrict__ out) {
    const int F = 128;
    int node = blockIdx.x * 8 + (threadIdx.x >> 5);
    if (node >= NNODES) return;
    int lane = threadIdx.x & 31;
    int f0 = lane * 4;
    int e0 = row_ptr[node];
    int e1 = row_ptr[node + 1];

    float acc0 = 0.f, acc1 = 0.f, acc2 = 0.f, acc3 = 0.f;
    const unsigned short* Hl = H + f0;

    int e = e0;
    for (; e + 3 < e1; e += 4) {
        int s0 = csr_src[e], s1 = csr_src[e + 1], s2 = csr_src[e + 2], s3 = csr_src[e + 3];
        ushort4 v0 = *(const ushort4*)(Hl + (size_t)s0 * F);
        ushort4 v1 = *(const ushort4*)(Hl + (size_t)s1 * F);
        ushort4 v2 = *(const ushort4*)(Hl + (size_t)s2 * F);
        ushort4 v3 = *(const ushort4*)(Hl + (size_t)s3 * F);
        acc0 += bf2f(v0.x) + bf2f(v1.x) + bf2f(v2.x) + bf2f(v3.x);
        acc1 += bf2f(v0.y) + bf2f(v1.y) + bf2f(v2.y) + bf2f(v3.y);
        acc2 += bf2f(v0.z) + bf2f(v1.z) + bf2f(v2.z) + bf2f(v3.z);
        acc3 += bf2f(v0.w) + bf2f(v1.w) + bf2f(v2.w) + bf2f(v3.w);
    }
    for (; e < e1; ++e) {
        int s = csr_src[e];
        ushort4 v = *(const ushort4*)(Hl + (size_t)s * F);
        acc0 += bf2f(v.x); acc1 += bf2f(v.y); acc2 += bf2f(v.z); acc3 += bf2f(v.w);
    }

    float nd = norm_dst[node];
    float4 o;
    o.x = fmaf(acc0, nd, bias[f0 + 0]);
    o.y = fmaf(acc1, nd, bias[f0 + 1]);
    o.z = fmaf(acc2, nd, bias[f0 + 2]);
    o.w = fmaf(acc3, nd, bias[f0 + 3]);
    *(float4*)(out + (size_t)node * F + f0) = o;
}

// ---------------- launch ----------------
extern "C" void kernel_launch(void* const* d_in, const int* in_sizes, int n_in,
                              void* d_out, int out_size, void* d_ws, size_t ws_size,
                              hipStream_t stream) {
    const float* x   = (const float*)d_in[0];
    const int*   src = (const int*)d_in[1];
    const int*   dst = (const int*)d_in[2];
    const float* W1  = (const float*)d_in[3];
    const float* b1  = (const float*)d_in[4];
    const float* W2  = (const float*)d_in[5];
    const float* b2  = (const float*)d_in[6];
    float* out = (float*)d_out;

    char* ws = (char*)d_ws;
    size_t off = 0;
    auto alloc = [&](size_t bytes) {
        char* p = ws + off;
        off += (bytes + 255) & ~(size_t)255;
        return p;
    };
    float* norm_src  = (float*)alloc(NNODES * 4);
    float* norm_dst  = (float*)alloc(NNODES * 4);
    int*   deg       = (int*)alloc((size_t)2 * NNODES * CPAD * 4);  // deg_out | deg_in (padded, contiguous)
    int*   deg_out   = deg;
    int*   deg_in    = deg + (size_t)NNODES * CPAD;
    int*   row_ptr   = (int*)alloc((NNODES + 256) * 4);
    int*   cursor    = (int*)alloc((size_t)NNODES * CPAD * 4);      // padded
    int*   blockSums = (int*)alloc(256 * 4);
    int*   csr_src   = (int*)alloc(NEDGES * 4);
    unsigned short* h   = (unsigned short*)alloc((size_t)NNODES * FH * 2);  // gemm1 out, reused as h2
    unsigned short* h1  = (unsigned short*)alloc((size_t)MPAD * FH * 2);    // agg1 out * norm_src (padded)
    unsigned short* Wt1 = (unsigned short*)alloc((size_t)FH * KDIM * 2);    // [256][256]
    unsigned short* Wt2 = (unsigned short*)alloc((size_t)FOUT * KDIM * 2);  // [128][256]
    unsigned short* h2  = h;                                                // [NNODES][FOUT]

    const int NB_N = (NNODES + 255) / 256;   // 196
    const int NB_E = (NEDGES + 255) / 256;   // 3125

    // one memset for both padded degree arrays (contiguous)
    hipMemsetAsync(deg, 0, (size_t)2 * NNODES * CPAD * 4, stream);

    cast_wt_both<<<96, 256, 0, stream>>>(W1, Wt1, W2, Wt2);
    deg_kernel<<<(NEDGES / 4 + 255) / 256, 256, 0, stream>>>(src, dst, deg_out, deg_in);
    scan1f<<<NB_N, 256, 0, stream>>>(deg_in, deg_out, norm_src, norm_dst, row_ptr, blockSums);
    scan2<<<1, 256, 0, stream>>>(blockSums, NB_N);
    scan3<<<NB_N, 256, 0, stream>>>(row_ptr, blockSums, cursor);
    fill_csr<<<NB_E, 256, 0, stream>>>(src, dst, cursor, csr_src);

    // layer 1: h = bf16((x*norm_src) @ W1)  (cast fused into GEMM A-staging)
    gemm_mfma<float, true><<<dim3(MPAD / 128, FH / 128), 256, 0, stream>>>(x, Wt1, norm_src, h, FH);
    // h1 = bf16(relu(agg(h)*norm_dst + b1) * norm_src); pad rows zeroed in-kernel
    agg1_kernel<<<MPAD / 4, 256, 0, stream>>>(h, row_ptr, csr_src, norm_dst, norm_src, b1, h1);

    // layer 2: h2 = bf16(h1 @ W2) ; out = agg(h2) * norm_dst + b2  (fp32 out)
    gemm_mfma<unsigned short, false><<<dim3(MPAD / 128, FOUT / 128), 256, 0, stream>>>(h1, Wt2, nullptr, h2, FOUT);
    agg2_kernel<<<(NNODES + 7) / 8, 256, 0, stream>>>(h2, row_ptr, csr_src, norm_dst, b2, out);
}

// Round 7
// 270.120 us; speedup vs baseline: 1.9740x; 1.2820x over previous
//
#include <hip/hip_runtime.h>

#define NNODES 50000
#define MPAD   50048    // padded to multiple of 128 for MFMA tiles
#define NEDGES 800000
#define KDIM   256      // in/hidden feature dim (GEMM K)
#define FH     256      // hidden feats
#define FOUT   128      // out feats

// ---- counting-sort geometry ----
#define SHIFT  8
#define NBUCK  196              // ceil(50000/256); max dst>>8 = 195
#define NB1    200              // level-1 blocks
#define EPB    4000             // edges per level-1 block (NB1*EPB == NEDGES)
#define CELLS  (NBUCK * NB1)    // 39200 per side
#define NSCAN  (2 * CELLS)      // 78400 (dst cells | src cells)
#define SCANB  ((NSCAN + 511) / 512)   // 154

typedef __bf16 bf16x8 __attribute__((ext_vector_type(8)));
typedef float floatx4 __attribute__((ext_vector_type(4)));

// ---------------- bf16 helpers (RNE) ----------------
__device__ __forceinline__ float bf2f(unsigned short u) {
    union { unsigned int i; float f; } v;
    v.i = ((unsigned int)u) << 16;
    return v.f;
}
__device__ __forceinline__ unsigned short f2bf(float f) {
    union { float f; unsigned int i; } v;
    v.f = f;
    unsigned int r = v.i + 0x7FFFu + ((v.i >> 16) & 1u);
    return (unsigned short)(r >> 16);
}

// ---------------- level-1: per-(block,bucket) histograms, no global atomics ----------------
__global__ __launch_bounds__(256) void l1_count(const int* __restrict__ src,
                                                const int* __restrict__ dst,
                                                int* __restrict__ cell) {
    __shared__ int histD[256], histS[256];
    const int b = blockIdx.x, tid = threadIdx.x;
    const int base = b * EPB;
    histD[tid] = 0; histS[tid] = 0;
    __syncthreads();
    for (int g = tid; g < EPB / 4; g += 256) {
        uint4 s4 = *(const uint4*)(src + base + g * 4);
        uint4 d4 = *(const uint4*)(dst + base + g * 4);
        atomicAdd(&histD[d4.x >> SHIFT], 1);
        atomicAdd(&histD[d4.y >> SHIFT], 1);
        atomicAdd(&histD[d4.z >> SHIFT], 1);
        atomicAdd(&histD[d4.w >> SHIFT], 1);
        atomicAdd(&histS[s4.x >> SHIFT], 1);
        atomicAdd(&histS[s4.y >> SHIFT], 1);
        atomicAdd(&histS[s4.z >> SHIFT], 1);
        atomicAdd(&histS[s4.w >> SHIFT], 1);
    }
    __syncthreads();
    if (tid < NBUCK) {
        cell[tid * NB1 + b] = histD[tid];
        cell[CELLS + tid * NB1 + b] = histS[tid];
    }
}

// ---------------- generic 3-kernel exclusive scan ----------------
__global__ __launch_bounds__(512) void scanA(int* __restrict__ data,
                                             int* __restrict__ sums, int n) {
    __shared__ int s[512];
    int tid = threadIdx.x;
    int i = blockIdx.x * 512 + tid;
    int v = (i < n) ? data[i] : 0;
    s[tid] = v;
    __syncthreads();
    for (int off = 1; off < 512; off <<= 1) {
        int t = (tid >= off) ? s[tid - off] : 0;
        __syncthreads();
        s[tid] += t;
        __syncthreads();
    }
    if (i < n) data[i] = s[tid] - v;
    if (tid == 511) sums[blockIdx.x] = s[511];
}

__global__ __launch_bounds__(512) void scanB(int* __restrict__ sums, int nb) {
    __shared__ int s[512];
    int tid = threadIdx.x;
    int v = (tid < nb) ? sums[tid] : 0;
    s[tid] = v;
    __syncthreads();
    for (int off = 1; off < 512; off <<= 1) {
        int t = (tid >= off) ? s[tid - off] : 0;
        __syncthreads();
        s[tid] += t;
        __syncthreads();
    }
    if (tid < nb) sums[tid] = s[tid] - v;
}

__global__ __launch_bounds__(512) void scanC(int* __restrict__ data,
                                             const int* __restrict__ sums, int n) {
    int i = blockIdx.x * 512 + threadIdx.x;
    if (i < n) data[i] += sums[blockIdx.x];
}

// ---------------- level-1 scatter: in-block counting sort, coalesced global writes --------
// tmp1[pos] = (src<<16)|dst, grouped by dst-bucket (global order = bucket-major, block-minor).
// tmp2[pos] = src&255, grouped by src-bucket.
__global__ __launch_bounds__(256) void l1_scatter(const int* __restrict__ src,
                                                  const int* __restrict__ dst,
                                                  const int* __restrict__ cell,  // scanned
                                                  unsigned int* __restrict__ tmp1,
                                                  unsigned char* __restrict__ tmp2) {
    __shared__ int histD[256], histS[256];        // counts -> cursors
    __shared__ int exD[256], exS[256];            // exclusive offsets (preserved)
    __shared__ unsigned int bufD[EPB];            // 16 KB sorted (src<<16)|dst
    __shared__ unsigned short bufS[EPB];          // 8 KB sorted src
    const int b = blockIdx.x, tid = threadIdx.x;
    const int base = b * EPB;

    histD[tid] = 0; histS[tid] = 0;
    __syncthreads();
    for (int g = tid; g < EPB / 4; g += 256) {
        uint4 s4 = *(const uint4*)(src + base + g * 4);
        uint4 d4 = *(const uint4*)(dst + base + g * 4);
        atomicAdd(&histD[d4.x >> SHIFT], 1);
        atomicAdd(&histD[d4.y >> SHIFT], 1);
        atomicAdd(&histD[d4.z >> SHIFT], 1);
        atomicAdd(&histD[d4.w >> SHIFT], 1);
        atomicAdd(&histS[s4.x >> SHIFT], 1);
        atomicAdd(&histS[s4.y >> SHIFT], 1);
        atomicAdd(&histS[s4.z >> SHIFT], 1);
        atomicAdd(&histS[s4.w >> SHIFT], 1);
    }
    __syncthreads();
    int vD = histD[tid], vS = histS[tid];
    exD[tid] = vD; exS[tid] = vS;
    __syncthreads();
    for (int off = 1; off < 256; off <<= 1) {
        int tD = (tid >= off) ? exD[tid - off] : 0;
        int tS = (tid >= off) ? exS[tid - off] : 0;
        __syncthreads();
        exD[tid] += tD; exS[tid] += tS;
        __syncthreads();
    }
    // inclusive -> exclusive; cursors start at exclusive
    int eD = exD[tid] - vD, eS = exS[tid] - vS;
    __syncthreads();
    exD[tid] = eD; exS[tid] = eS;
    histD[tid] = eD; histS[tid] = eS;
    __syncthreads();
    // sort into LDS
    for (int g = tid; g < EPB / 4; g += 256) {
        uint4 s4 = *(const uint4*)(src + base + g * 4);
        uint4 d4 = *(const uint4*)(dst + base + g * 4);
        unsigned int ss[4] = {s4.x, s4.y, s4.z, s4.w};
        unsigned int dd[4] = {d4.x, d4.y, d4.z, d4.w};
#pragma unroll
        for (int j = 0; j < 4; ++j) {
            int p = atomicAdd(&histD[dd[j] >> SHIFT], 1);
            bufD[p] = (ss[j] << 16) | dd[j];
            int q = atomicAdd(&histS[ss[j] >> SHIFT], 1);
            bufS[q] = (unsigned short)ss[j];
        }
    }
    __syncthreads();
    // coalesced write-out: global pos = cell[k*NB1+b] + (e - excl[k])
    for (int e = tid; e < EPB; e += 256) {
        unsigned int p = bufD[e];
        int k = (p & 0xFFFFu) >> SHIFT;
        tmp1[cell[k * NB1 + b] + (e - exD[k])] = p;
    }
    for (int e = tid; e < EPB; e += 256) {
        unsigned int s = bufS[e];
        int k = s >> SHIFT;
        tmp2[(cell[CELLS + k * NB1 + b] - NEDGES) + (e - exS[k])] = (unsigned char)(s & 255u);
    }
}

// ---------------- level-2 dst: exact counts + row_ptr + norm_dst + csr scatter ------------
__global__ __launch_bounds__(256) void l2_dst(const unsigned int* __restrict__ tmp1,
                                              const int* __restrict__ cell,
                                              int* __restrict__ row_ptr,
                                              float* __restrict__ norm_dst,
                                              int* __restrict__ csr_src) {
    __shared__ int cnt[256], ofs[256], cur[256];
    const int k = blockIdx.x, tid = threadIdx.x;
    const int start = cell[k * NB1];
    const int end = (k + 1 < NBUCK) ? cell[(k + 1) * NB1] : NEDGES;
    cnt[tid] = 0;
    __syncthreads();
    for (int e = start + tid; e < end; e += 256)
        atomicAdd(&cnt[tmp1[e] & 255u], 1);
    __syncthreads();
    int v = cnt[tid];
    ofs[tid] = v;
    __syncthreads();
    for (int off = 1; off < 256; off <<= 1) {
        int t = (tid >= off) ? ofs[tid - off] : 0;
        __syncthreads();
        ofs[tid] += t;
        __syncthreads();
    }
    int excl = ofs[tid] - v;
    int node = k * 256 + tid;
    if (node < NNODES) {
        row_ptr[node] = start + excl;
        int d = v < 1 ? 1 : v;
        norm_dst[node] = 1.0f / sqrtf((float)d);
    }
    cur[tid] = start + excl;
    if (k == 0 && tid == 0) row_ptr[NNODES] = NEDGES;
    __syncthreads();
    for (int e = start + tid; e < end; e += 256) {
        unsigned int p = tmp1[e];
        int pos = atomicAdd(&cur[p & 255u], 1);
        csr_src[pos] = (int)(p >> 16);
    }
}

// ---------------- level-2 src: counts -> norm_src ----------------
__global__ __launch_bounds__(256) void l2_src(const unsigned char* __restrict__ tmp2,
                                              const int* __restrict__ cell,
                                              float* __restrict__ norm_src) {
    __shared__ int cnt[256];
    const int k = blockIdx.x, tid = threadIdx.x;
    const int start = cell[CELLS + k * NB1] - NEDGES;
    const int end = (k + 1 < NBUCK) ? cell[CELLS + (k + 1) * NB1] - NEDGES : NEDGES;
    cnt[tid] = 0;
    __syncthreads();
    for (int e = start + tid; e < end; e += 256)
        atomicAdd(&cnt[tmp2[e]], 1);
    __syncthreads();
    int node = k * 256 + tid;
    if (node < NNODES) {
        int d = cnt[tid] < 1 ? 1 : cnt[tid];
        norm_src[node] = 1.0f / sqrtf((float)d);
    }
}

// ---------------- W1,W2 [K][N] -> Wt [N][K] bf16 (one kernel, LDS 32x32 transpose) --------
__global__ __launch_bounds__(256) void cast_wt_both(const float* __restrict__ W1,
                                                    unsigned short* __restrict__ Wt1,
                                                    const float* __restrict__ W2,
                                                    unsigned short* __restrict__ Wt2) {
    __shared__ float tile[32][33];
    int b = blockIdx.x;
    const float* W; unsigned short* Wt; int N;
    if (b < 64) { W = W1; Wt = Wt1; N = FH; }
    else        { b -= 64; W = W2; Wt = Wt2; N = FOUT; }
    int kt = (b & 7) * 32;
    int nt = (b >> 3) * 32;
    int tx = threadIdx.x & 31;
    int ty = threadIdx.x >> 5;
    for (int r = ty; r < 32; r += 8)
        tile[r][tx] = W[(size_t)(kt + r) * N + nt + tx];
    __syncthreads();
    for (int r = ty; r < 32; r += 8)
        Wt[(size_t)(nt + r) * KDIM + kt + tx] = f2bf(tile[tx][r]);
}

// ---------------- A-staging loaders (8 bf16 = 16B, packed in uint4) ----------------
__device__ __forceinline__ uint4 stage_a8(const float* A, int row, int k, float scale, bool valid) {
    if (!valid) return make_uint4(0u, 0u, 0u, 0u);
    const float* p = A + (size_t)row * KDIM + k;
    float4 v0 = *(const float4*)p;
    float4 v1 = *(const float4*)(p + 4);
    union { uint4 u; unsigned short s[8]; } r;
    r.s[0] = f2bf(v0.x * scale); r.s[1] = f2bf(v0.y * scale);
    r.s[2] = f2bf(v0.z * scale); r.s[3] = f2bf(v0.w * scale);
    r.s[4] = f2bf(v1.x * scale); r.s[5] = f2bf(v1.y * scale);
    r.s[6] = f2bf(v1.z * scale); r.s[7] = f2bf(v1.w * scale);
    return r.u;
}
__device__ __forceinline__ uint4 stage_a8(const unsigned short* A, int row, int k, float, bool) {
    return *(const uint4*)(A + (size_t)row * KDIM + k);
}

// ---------------- bf16 MFMA GEMM: C[M,N] = (A[M,256] * norm?) @ Bt[N,256]^T ----------------
// 128x128 tile, BK=32, 256 threads = 4 waves, each wave 64x64 via 4x4 of 16x16x32 MFMA.
// Layout (HW-verified; R4 probe matched bit-exact): A-frag m=lane&15, k=(lane>>4)*8+j;
// C/D col=lane&15, row=(lane>>4)*4+reg.
template <typename TA, bool SCALE>
__global__ __launch_bounds__(256) void gemm_mfma(const TA* __restrict__ A,
                                                 const unsigned short* __restrict__ Bt,
                                                 const float* __restrict__ norm,
                                                 unsigned short* __restrict__ C,
                                                 int N) {
    __shared__ __align__(16) unsigned short As[128][32];
    __shared__ __align__(16) unsigned short Bs[128][32];

    const int tid = threadIdx.x;
    const int lane = tid & 63;
    const int wave = tid >> 6;
    const int wm = wave & 1, wn = wave >> 1;
    const int m0 = blockIdx.x * 128;
    const int n0 = blockIdx.y * 128;

    const int srow = tid >> 2;
    const int sk = (tid & 3) << 3;

    const int r0 = m0 + srow;
    const int r1 = r0 + 64;
    bool va0 = true, va1 = true;
    float sc0 = 0.f, sc1 = 0.f;
    if (SCALE) {
        va0 = (r0 < NNODES); va1 = (r1 < NNODES);
        sc0 = va0 ? norm[r0] : 0.f;
        sc1 = va1 ? norm[r1] : 0.f;
    }

    const unsigned short* Bg = Bt + (size_t)(n0 + srow) * KDIM + sk;

    floatx4 acc[4][4] = {};

    const int ar = wm * 64 + (lane & 15);
    const int br = wn * 64 + (lane & 15);
    const int fk = (lane >> 4) << 3;

    for (int kk = 0; kk < KDIM; kk += 32) {
        uint4 a0 = stage_a8(A, va0 ? r0 : 0, kk + sk, sc0, va0);
        uint4 a1 = stage_a8(A, va1 ? r1 : 0, kk + sk, sc1, va1);
        uint4 b0 = *(const uint4*)(Bg + kk);
        uint4 b1 = *(const uint4*)(Bg + (size_t)64 * KDIM + kk);
        __syncthreads();
        *(uint4*)&As[srow][sk] = a0;
        *(uint4*)&As[srow + 64][sk] = a1;
        *(uint4*)&Bs[srow][sk] = b0;
        *(uint4*)&Bs[srow + 64][sk] = b1;
        __syncthreads();

        bf16x8 af[4], bfr[4];
#pragma unroll
        for (int i = 0; i < 4; ++i) {
            af[i]  = *(const bf16x8*)&As[ar + i * 16][fk];
            bfr[i] = *(const bf16x8*)&Bs[br + i * 16][fk];
        }
#pragma unroll
        for (int i = 0; i < 4; ++i)
#pragma unroll
            for (int j = 0; j < 4; ++j)
                acc[i][j] = __builtin_amdgcn_mfma_f32_16x16x32_bf16(af[i], bfr[j], acc[i][j], 0, 0, 0);
    }

    const int rb = (lane >> 4) << 2;
    const int cc = lane & 15;
#pragma unroll
    for (int i = 0; i < 4; ++i) {
        int mb = m0 + wm * 64 + i * 16 + rb;
#pragma unroll
        for (int j = 0; j < 4; ++j) {
            int col = n0 + wn * 64 + j * 16 + cc;
#pragma unroll
            for (int r = 0; r < 4; ++r) {
                int m = mb + r;
                if (m < NNODES)
                    C[(size_t)m * N + col] = f2bf(acc[i][j][r]);
            }
        }
    }
}

// ---------------- agg layer 1: bf16 in (F=256), bf16 out.
// h1[node] = relu(agg * norm_dst + b1) * norm_src; pad rows write zeros.
__global__ __launch_bounds__(256) void agg1_kernel(const unsigned short* __restrict__ H,
                                                   const int* __restrict__ row_ptr,
                                                   const int* __restrict__ csr_src,
                                                   const float* __restrict__ norm_dst,
                                                   const float* __restrict__ norm_src,
                                                   const float* __restrict__ bias,
                                                   unsigned short* __restrict__ out) {
    const int F = 256;
    int node = blockIdx.x * 4 + (threadIdx.x >> 6);
    int lane = threadIdx.x & 63;
    int f0 = lane * 4;
    if (node >= NNODES) {
        if (node < MPAD) {
            ushort4 z = {0, 0, 0, 0};
            *(ushort4*)(out + (size_t)node * F + f0) = z;
        }
        return;
    }
    int e0 = row_ptr[node];
    int e1 = row_ptr[node + 1];

    float acc0 = 0.f, acc1 = 0.f, acc2 = 0.f, acc3 = 0.f;
    const unsigned short* Hl = H + f0;

    int e = e0;
    for (; e + 3 < e1; e += 4) {
        int s0 = csr_src[e], s1 = csr_src[e + 1], s2 = csr_src[e + 2], s3 = csr_src[e + 3];
        ushort4 v0 = *(const ushort4*)(Hl + (size_t)s0 * F);
        ushort4 v1 = *(const ushort4*)(Hl + (size_t)s1 * F);
        ushort4 v2 = *(const ushort4*)(Hl + (size_t)s2 * F);
        ushort4 v3 = *(const ushort4*)(Hl + (size_t)s3 * F);
        acc0 += bf2f(v0.x) + bf2f(v1.x) + bf2f(v2.x) + bf2f(v3.x);
        acc1 += bf2f(v0.y) + bf2f(v1.y) + bf2f(v2.y) + bf2f(v3.y);
        acc2 += bf2f(v0.z) + bf2f(v1.z) + bf2f(v2.z) + bf2f(v3.z);
        acc3 += bf2f(v0.w) + bf2f(v1.w) + bf2f(v2.w) + bf2f(v3.w);
    }
    for (; e < e1; ++e) {
        int s = csr_src[e];
        ushort4 v = *(const ushort4*)(Hl + (size_t)s * F);
        acc0 += bf2f(v.x); acc1 += bf2f(v.y); acc2 += bf2f(v.z); acc3 += bf2f(v.w);
    }

    float nd = norm_dst[node];
    float ns = norm_src[node];
    float o0 = fmaxf(fmaf(acc0, nd, bias[f0 + 0]), 0.0f) * ns;
    float o1 = fmaxf(fmaf(acc1, nd, bias[f0 + 1]), 0.0f) * ns;
    float o2 = fmaxf(fmaf(acc2, nd, bias[f0 + 2]), 0.0f) * ns;
    float o3 = fmaxf(fmaf(acc3, nd, bias[f0 + 3]), 0.0f) * ns;
    ushort4 o;
    o.x = f2bf(o0); o.y = f2bf(o1); o.z = f2bf(o2); o.w = f2bf(o3);
    *(ushort4*)(out + (size_t)node * F + f0) = o;
}

// ---------------- agg layer 2: bf16 in (F=128), fp32 out, no relu. ----------------
__global__ __launch_bounds__(256) void agg2_kernel(const unsigned short* __restrict__ H,
                                                   const int* __restrict__ row_ptr,
                                                   const int* __restrict__ csr_src,
                                                   const float* __restrict__ norm_dst,
                                                   const float* __restrict__ bias,
                                                   float* __restrict__ out) {
    const int F = 128;
    int node = blockIdx.x * 8 + (threadIdx.x >> 5);
    if (node >= NNODES) return;
    int lane = threadIdx.x & 31;
    int f0 = lane * 4;
    int e0 = row_ptr[node];
    int e1 = row_ptr[node + 1];

    float acc0 = 0.f, acc1 = 0.f, acc2 = 0.f, acc3 = 0.f;
    const unsigned short* Hl = H + f0;

    int e = e0;
    for (; e + 3 < e1; e += 4) {
        int s0 = csr_src[e], s1 = csr_src[e + 1], s2 = csr_src[e + 2], s3 = csr_src[e + 3];
        ushort4 v0 = *(const ushort4*)(Hl + (size_t)s0 * F);
        ushort4 v1 = *(const ushort4*)(Hl + (size_t)s1 * F);
        ushort4 v2 = *(const ushort4*)(Hl + (size_t)s2 * F);
        ushort4 v3 = *(const ushort4*)(Hl + (size_t)s3 * F);
        acc0 += bf2f(v0.x) + bf2f(v1.x) + bf2f(v2.x) + bf2f(v3.x);
        acc1 += bf2f(v0.y) + bf2f(v1.y) + bf2f(v2.y) + bf2f(v3.y);
        acc2 += bf2f(v0.z) + bf2f(v1.z) + bf2f(v2.z) + bf2f(v3.z);
        acc3 += bf2f(v0.w) + bf2f(v1.w) + bf2f(v2.w) + bf2f(v3.w);
    }
    for (; e < e1; ++e) {
        int s = csr_src[e];
        ushort4 v = *(const ushort4*)(Hl + (size_t)s * F);
        acc0 += bf2f(v.x); acc1 += bf2f(v.y); acc2 += bf2f(v.z); acc3 += bf2f(v.w);
    }

    float nd = norm_dst[node];
    float4 o;
    o.x = fmaf(acc0, nd, bias[f0 + 0]);
    o.y = fmaf(acc1, nd, bias[f0 + 1]);
    o.z = fmaf(acc2, nd, bias[f0 + 2]);
    o.w = fmaf(acc3, nd, bias[f0 + 3]);
    *(float4*)(out + (size_t)node * F + f0) = o;
}

// ---------------- launch ----------------
extern "C" void kernel_launch(void* const* d_in, const int* in_sizes, int n_in,
                              void* d_out, int out_size, void* d_ws, size_t ws_size,
                              hipStream_t stream) {
    const float* x   = (const float*)d_in[0];
    const int*   src = (const int*)d_in[1];
    const int*   dst = (const int*)d_in[2];
    const float* W1  = (const float*)d_in[3];
    const float* b1  = (const float*)d_in[4];
    const float* W2  = (const float*)d_in[5];
    const float* b2  = (const float*)d_in[6];
    float* out = (float*)d_out;

    char* ws = (char*)d_ws;
    size_t off = 0;
    auto alloc = [&](size_t bytes) {
        char* p = ws + off;
        off += (bytes + 255) & ~(size_t)255;
        return p;
    };
    float* norm_src  = (float*)alloc(NNODES * 4);
    float* norm_dst  = (float*)alloc(NNODES * 4);
    int*   cell      = (int*)alloc((size_t)NSCAN * 4);        // (bucket,block) cells, dst | src
    int*   ssum      = (int*)alloc(512 * 4);
    unsigned int*  tmp1 = (unsigned int*)alloc((size_t)NEDGES * 4);   // (src<<16)|dst by dst-bucket
    unsigned char* tmp2 = (unsigned char*)alloc((size_t)NEDGES);      // src&255 by src-bucket
    int*   row_ptr   = (int*)alloc((NNODES + 16) * 4);
    int*   csr_src   = (int*)alloc(NEDGES * 4);
    unsigned short* h   = (unsigned short*)alloc((size_t)NNODES * FH * 2);  // gemm1 out, reused as h2
    unsigned short* h1  = (unsigned short*)alloc((size_t)MPAD * FH * 2);    // agg1 out * norm_src (padded)
    unsigned short* Wt1 = (unsigned short*)alloc((size_t)FH * KDIM * 2);
    unsigned short* Wt2 = (unsigned short*)alloc((size_t)FOUT * KDIM * 2);
    unsigned short* h2  = h;

    // weights cast (independent)
    cast_wt_both<<<96, 256, 0, stream>>>(W1, Wt1, W2, Wt2);

    // atomic-free CSR build: count -> scan -> bucket-sorted scatter -> per-bucket finalize
    l1_count<<<NB1, 256, 0, stream>>>(src, dst, cell);
    scanA<<<SCANB, 512, 0, stream>>>(cell, ssum, NSCAN);
    scanB<<<1, 512, 0, stream>>>(ssum, SCANB);
    scanC<<<SCANB, 512, 0, stream>>>(cell, ssum, NSCAN);
    l1_scatter<<<NB1, 256, 0, stream>>>(src, dst, cell, tmp1, tmp2);
    l2_dst<<<NBUCK, 256, 0, stream>>>(tmp1, cell, row_ptr, norm_dst, csr_src);
    l2_src<<<NBUCK, 256, 0, stream>>>(tmp2, cell, norm_src);

    // layer 1: h = bf16((x*norm_src) @ W1)  (cast fused into GEMM A-staging)
    gemm_mfma<float, true><<<dim3(MPAD / 128, FH / 128), 256, 0, stream>>>(x, Wt1, norm_src, h, FH);
    agg1_kernel<<<MPAD / 4, 256, 0, stream>>>(h, row_ptr, csr_src, norm_dst, norm_src, b1, h1);

    // layer 2: h2 = bf16(h1 @ W2) ; out = agg(h2) * norm_dst + b2  (fp32 out)
    gemm_mfma<unsigned short, false><<<dim3(MPAD / 128, FOUT / 128), 256, 0, stream>>>(h1, Wt2, nullptr, h2, FOUT);
    agg2_kernel<<<(NNODES + 7) / 8, 256, 0, stream>>>(h2, row_ptr, csr_src, norm_dst, b2, out);
}